// Round 1
// baseline (374.060 us; speedup 1.0000x reference)
//
#include <hip/hip_runtime.h>
#include <hip/hip_bf16.h>

// Trilinear interpolation: input [16][128][128][128] fp32, coords [N][3] in [-1,1],
// out [16][N] fp32.
//
// Strategy: transpose input to channel-last [128^3][16] in d_ws so each corner's
// 16 channel values are one contiguous 64B cache line; then one thread per point
// gathers 8 corners x 4 float4 and writes 16 coalesced strided outputs.

#define GD   128
#define NCH  16
constexpr int VOX = GD * GD * GD;

// ---------------- transpose: [c][s] -> [s][c] ----------------
__global__ __launch_bounds__(256) void transpose_k(const float* __restrict__ in,
                                                   float* __restrict__ ws) {
    int s = blockIdx.x * 256 + threadIdx.x;   // spatial index, grid sized exactly
    float v[NCH];
#pragma unroll
    for (int c = 0; c < NCH; ++c)
        v[c] = in[(size_t)c * VOX + s];       // coalesced read per channel
    float4* o = (float4*)(ws + (size_t)s * NCH);  // 64B/lane, fully coalesced write
    o[0] = make_float4(v[0],  v[1],  v[2],  v[3]);
    o[1] = make_float4(v[4],  v[5],  v[6],  v[7]);
    o[2] = make_float4(v[8],  v[9],  v[10], v[11]);
    o[3] = make_float4(v[12], v[13], v[14], v[15]);
}

__device__ __forceinline__ void fma4(float4& a, float w, const float4 v) {
    a.x += w * v.x; a.y += w * v.y; a.z += w * v.z; a.w += w * v.w;
}

// ---------------- interp from channel-last workspace ----------------
__global__ __launch_bounds__(256) void interp_k(const float* __restrict__ ws,
                                                const float* __restrict__ coords,
                                                float* __restrict__ out, int N) {
    int n = blockIdx.x * 256 + threadIdx.x;
    if (n >= N) return;

    float cx = (coords[3 * n + 0] + 1.0f) * 0.5f * (float)(GD - 1);
    float cy = (coords[3 * n + 1] + 1.0f) * 0.5f * (float)(GD - 1);
    float cz = (coords[3 * n + 2] + 1.0f) * 0.5f * (float)(GD - 1);

    float fx = floorf(cx), fy = floorf(cy), fz = floorf(cz);
    float tx = cx - fx, ty = cy - fy, tz = cz - fz;
    int ix = (int)fx, iy = (int)fy, iz = (int)fz;

    int ix0 = min(max(ix,     0), GD - 1), ix1 = min(max(ix + 1, 0), GD - 1);
    int iy0 = min(max(iy,     0), GD - 1), iy1 = min(max(iy + 1, 0), GD - 1);
    int iz0 = min(max(iz,     0), GD - 1), iz1 = min(max(iz + 1, 0), GD - 1);

    float wx0 = 1.0f - tx, wx1 = tx;
    float wy0 = 1.0f - ty, wy1 = ty;
    float wz0 = 1.0f - tz, wz1 = tz;

    size_t bx0 = (size_t)ix0 * (GD * GD * NCH), bx1 = (size_t)ix1 * (GD * GD * NCH);
    size_t by0 = (size_t)iy0 * (GD * NCH),      by1 = (size_t)iy1 * (GD * NCH);
    size_t bz0 = (size_t)iz0 * NCH,             bz1 = (size_t)iz1 * NCH;

    float4 a0 = {0,0,0,0}, a1 = {0,0,0,0}, a2 = {0,0,0,0}, a3 = {0,0,0,0};

#define CORNER(BX, BY, BZ, W)                                        \
    {                                                                \
        const float4* p = (const float4*)(ws + (BX) + (BY) + (BZ));  \
        float w = (W);                                               \
        fma4(a0, w, p[0]); fma4(a1, w, p[1]);                        \
        fma4(a2, w, p[2]); fma4(a3, w, p[3]);                        \
    }

    CORNER(bx0, by0, bz0, wx0 * wy0 * wz0)
    CORNER(bx0, by0, bz1, wx0 * wy0 * wz1)
    CORNER(bx0, by1, bz0, wx0 * wy1 * wz0)
    CORNER(bx0, by1, bz1, wx0 * wy1 * wz1)
    CORNER(bx1, by0, bz0, wx1 * wy0 * wz0)
    CORNER(bx1, by0, bz1, wx1 * wy0 * wz1)
    CORNER(bx1, by1, bz0, wx1 * wy1 * wz0)
    CORNER(bx1, by1, bz1, wx1 * wy1 * wz1)
#undef CORNER

    // out[c*N + n]: each store coalesced across the wave
    out[(size_t)0  * N + n] = a0.x; out[(size_t)1  * N + n] = a0.y;
    out[(size_t)2  * N + n] = a0.z; out[(size_t)3  * N + n] = a0.w;
    out[(size_t)4  * N + n] = a1.x; out[(size_t)5  * N + n] = a1.y;
    out[(size_t)6  * N + n] = a1.z; out[(size_t)7  * N + n] = a1.w;
    out[(size_t)8  * N + n] = a2.x; out[(size_t)9  * N + n] = a2.y;
    out[(size_t)10 * N + n] = a2.z; out[(size_t)11 * N + n] = a2.w;
    out[(size_t)12 * N + n] = a3.x; out[(size_t)13 * N + n] = a3.y;
    out[(size_t)14 * N + n] = a3.z; out[(size_t)15 * N + n] = a3.w;
}

// ---------------- fallback: direct gather from native layout ----------------
__global__ __launch_bounds__(256) void interp_direct_k(const float* __restrict__ in,
                                                       const float* __restrict__ coords,
                                                       float* __restrict__ out, int N) {
    int n = blockIdx.x * 256 + threadIdx.x;
    if (n >= N) return;

    float cx = (coords[3 * n + 0] + 1.0f) * 0.5f * (float)(GD - 1);
    float cy = (coords[3 * n + 1] + 1.0f) * 0.5f * (float)(GD - 1);
    float cz = (coords[3 * n + 2] + 1.0f) * 0.5f * (float)(GD - 1);

    float fx = floorf(cx), fy = floorf(cy), fz = floorf(cz);
    float tx = cx - fx, ty = cy - fy, tz = cz - fz;
    int ix = (int)fx, iy = (int)fy, iz = (int)fz;

    int ix0 = min(max(ix,     0), GD - 1), ix1 = min(max(ix + 1, 0), GD - 1);
    int iy0 = min(max(iy,     0), GD - 1), iy1 = min(max(iy + 1, 0), GD - 1);
    int iz0 = min(max(iz,     0), GD - 1), iz1 = min(max(iz + 1, 0), GD - 1);

    float wx0 = 1.0f - tx, wx1 = tx;
    float wy0 = 1.0f - ty, wy1 = ty;
    float wz0 = 1.0f - tz, wz1 = tz;

    int o000 = (ix0 * GD + iy0) * GD + iz0, o001 = (ix0 * GD + iy0) * GD + iz1;
    int o010 = (ix0 * GD + iy1) * GD + iz0, o011 = (ix0 * GD + iy1) * GD + iz1;
    int o100 = (ix1 * GD + iy0) * GD + iz0, o101 = (ix1 * GD + iy0) * GD + iz1;
    int o110 = (ix1 * GD + iy1) * GD + iz0, o111 = (ix1 * GD + iy1) * GD + iz1;

    float w000 = wx0 * wy0 * wz0, w001 = wx0 * wy0 * wz1;
    float w010 = wx0 * wy1 * wz0, w011 = wx0 * wy1 * wz1;
    float w100 = wx1 * wy0 * wz0, w101 = wx1 * wy0 * wz1;
    float w110 = wx1 * wy1 * wz0, w111 = wx1 * wy1 * wz1;

#pragma unroll
    for (int c = 0; c < NCH; ++c) {
        const float* g = in + (size_t)c * VOX;
        float acc = w000 * g[o000] + w001 * g[o001] + w010 * g[o010] + w011 * g[o011]
                  + w100 * g[o100] + w101 * g[o101] + w110 * g[o110] + w111 * g[o111];
        out[(size_t)c * N + n] = acc;
    }
}

extern "C" void kernel_launch(void* const* d_in, const int* in_sizes, int n_in,
                              void* d_out, int out_size, void* d_ws, size_t ws_size,
                              hipStream_t stream) {
    const float* input  = (const float*)d_in[0];
    const float* coords = (const float*)d_in[1];
    float* out = (float*)d_out;
    int N = in_sizes[1] / 3;  // 1,000,000

    size_t need = (size_t)VOX * NCH * sizeof(float);  // 134 MB channel-last copy
    if (ws_size >= need) {
        transpose_k<<<VOX / 256, 256, 0, stream>>>(input, (float*)d_ws);
        interp_k<<<(N + 255) / 256, 256, 0, stream>>>((const float*)d_ws, coords, out, N);
    } else {
        interp_direct_k<<<(N + 255) / 256, 256, 0, stream>>>(input, coords, out, N);
    }
}

// Round 2
// 355.745 us; speedup vs baseline: 1.0515x; 1.0515x over previous
//
#include <hip/hip_runtime.h>
#include <hip/hip_bf16.h>

// Trilinear interpolation: input [16][128][128][128] fp32, coords [N][3] in [-1,1],
// out [16][N] fp32.
//
// R2 strategy: transpose+quantize input to bf16 channel-last [128^3][16] in d_ws
// (32 B/voxel -> one corner = half a cache line, z-pair = one line; ws = 67 MB,
// L3-resident). Interp gathers 8 corners x 32 B, converts bf16->fp32 by shift,
// accumulates fp32. Halves both transpose and gather traffic vs R1's fp32 ws.

#define GD   128
#define NCH  16
constexpr int VOX = GD * GD * GD;

__device__ __forceinline__ unsigned short f2bf_rne(float f) {
    unsigned u = __builtin_bit_cast(unsigned, f);
    u = u + 0x7fffu + ((u >> 16) & 1u);   // round-nearest-even
    return (unsigned short)(u >> 16);
}

// ---------- transpose+quantize: [c][s] fp32 -> [s][c] bf16, 4 voxels/thread ----------
__global__ __launch_bounds__(256) void transpose_bf16_k(const float* __restrict__ in,
                                                        unsigned short* __restrict__ ws) {
    int t = blockIdx.x * 256 + threadIdx.x;   // grid sized exactly: VOX/4 threads
    int s = t * 4;
    float4 v[NCH];
#pragma unroll
    for (int c = 0; c < NCH; ++c)
        v[c] = *(const float4*)(in + (size_t)c * VOX + s);   // 16 B/lane coalesced

    const float* vf = (const float*)v;        // vf[c*4 + j]
#pragma unroll
    for (int j = 0; j < 4; ++j) {
        unsigned p[8];
#pragma unroll
        for (int k = 0; k < 8; ++k) {
            unsigned lo = f2bf_rne(vf[(2 * k + 0) * 4 + j]);
            unsigned hi = f2bf_rne(vf[(2 * k + 1) * 4 + j]);
            p[k] = lo | (hi << 16);
        }
        uint4* o = (uint4*)(ws + (size_t)(s + j) * NCH);
        o[0] = make_uint4(p[0], p[1], p[2], p[3]);
        o[1] = make_uint4(p[4], p[5], p[6], p[7]);
    }
}

// ---------- interp from bf16 channel-last workspace ----------
__global__ __launch_bounds__(256) void interp_bf16_k(const unsigned short* __restrict__ ws,
                                                     const float* __restrict__ coords,
                                                     float* __restrict__ out, int N) {
    int n = blockIdx.x * 256 + threadIdx.x;
    if (n >= N) return;

    float cx = (coords[3 * n + 0] + 1.0f) * 0.5f * (float)(GD - 1);
    float cy = (coords[3 * n + 1] + 1.0f) * 0.5f * (float)(GD - 1);
    float cz = (coords[3 * n + 2] + 1.0f) * 0.5f * (float)(GD - 1);

    float fx = floorf(cx), fy = floorf(cy), fz = floorf(cz);
    float tx = cx - fx, ty = cy - fy, tz = cz - fz;
    int ix = (int)fx, iy = (int)fy, iz = (int)fz;

    int ix0 = min(max(ix,     0), GD - 1), ix1 = min(max(ix + 1, 0), GD - 1);
    int iy0 = min(max(iy,     0), GD - 1), iy1 = min(max(iy + 1, 0), GD - 1);
    int iz0 = min(max(iz,     0), GD - 1), iz1 = min(max(iz + 1, 0), GD - 1);

    float wx0 = 1.0f - tx, wx1 = tx;
    float wy0 = 1.0f - ty, wy1 = ty;
    float wz0 = 1.0f - tz, wz1 = tz;

    size_t bx0 = (size_t)ix0 * (GD * GD * NCH), bx1 = (size_t)ix1 * (GD * GD * NCH);
    size_t by0 = (size_t)iy0 * (GD * NCH),      by1 = (size_t)iy1 * (GD * NCH);
    size_t bz0 = (size_t)iz0 * NCH,             bz1 = (size_t)iz1 * NCH;

    float acc[NCH];
#pragma unroll
    for (int c = 0; c < NCH; ++c) acc[c] = 0.0f;

#define CORNER(BX, BY, BZ, W)                                                  \
    {                                                                          \
        const uint4* p = (const uint4*)(ws + (BX) + (BY) + (BZ));              \
        uint4 A = p[0], B = p[1];                                              \
        unsigned u[8] = {A.x, A.y, A.z, A.w, B.x, B.y, B.z, B.w};              \
        float w = (W);                                                         \
        _Pragma("unroll")                                                      \
        for (int k = 0; k < 8; ++k) {                                          \
            float lo = __builtin_bit_cast(float, u[k] << 16);                  \
            float hi = __builtin_bit_cast(float, u[k] & 0xffff0000u);          \
            acc[2 * k + 0] += w * lo;                                          \
            acc[2 * k + 1] += w * hi;                                          \
        }                                                                      \
    }

    CORNER(bx0, by0, bz0, wx0 * wy0 * wz0)
    CORNER(bx0, by0, bz1, wx0 * wy0 * wz1)
    CORNER(bx0, by1, bz0, wx0 * wy1 * wz0)
    CORNER(bx0, by1, bz1, wx0 * wy1 * wz1)
    CORNER(bx1, by0, bz0, wx1 * wy0 * wz0)
    CORNER(bx1, by0, bz1, wx1 * wy0 * wz1)
    CORNER(bx1, by1, bz0, wx1 * wy1 * wz0)
    CORNER(bx1, by1, bz1, wx1 * wy1 * wz1)
#undef CORNER

#pragma unroll
    for (int c = 0; c < NCH; ++c)
        out[(size_t)c * N + n] = acc[c];   // coalesced strided stores
}

// ---------- fallback: direct gather from native layout (fp32) ----------
__global__ __launch_bounds__(256) void interp_direct_k(const float* __restrict__ in,
                                                       const float* __restrict__ coords,
                                                       float* __restrict__ out, int N) {
    int n = blockIdx.x * 256 + threadIdx.x;
    if (n >= N) return;

    float cx = (coords[3 * n + 0] + 1.0f) * 0.5f * (float)(GD - 1);
    float cy = (coords[3 * n + 1] + 1.0f) * 0.5f * (float)(GD - 1);
    float cz = (coords[3 * n + 2] + 1.0f) * 0.5f * (float)(GD - 1);

    float fx = floorf(cx), fy = floorf(cy), fz = floorf(cz);
    float tx = cx - fx, ty = cy - fy, tz = cz - fz;
    int ix = (int)fx, iy = (int)fy, iz = (int)fz;

    int ix0 = min(max(ix,     0), GD - 1), ix1 = min(max(ix + 1, 0), GD - 1);
    int iy0 = min(max(iy,     0), GD - 1), iy1 = min(max(iy + 1, 0), GD - 1);
    int iz0 = min(max(iz,     0), GD - 1), iz1 = min(max(iz + 1, 0), GD - 1);

    float wx0 = 1.0f - tx, wx1 = tx;
    float wy0 = 1.0f - ty, wy1 = ty;
    float wz0 = 1.0f - tz, wz1 = tz;

    int o000 = (ix0 * GD + iy0) * GD + iz0, o001 = (ix0 * GD + iy0) * GD + iz1;
    int o010 = (ix0 * GD + iy1) * GD + iz0, o011 = (ix0 * GD + iy1) * GD + iz1;
    int o100 = (ix1 * GD + iy0) * GD + iz0, o101 = (ix1 * GD + iy0) * GD + iz1;
    int o110 = (ix1 * GD + iy1) * GD + iz0, o111 = (ix1 * GD + iy1) * GD + iz1;

    float w000 = wx0 * wy0 * wz0, w001 = wx0 * wy0 * wz1;
    float w010 = wx0 * wy1 * wz0, w011 = wx0 * wy1 * wz1;
    float w100 = wx1 * wy0 * wz0, w101 = wx1 * wy0 * wz1;
    float w110 = wx1 * wy1 * wz0, w111 = wx1 * wy1 * wz1;

#pragma unroll
    for (int c = 0; c < NCH; ++c) {
        const float* g = in + (size_t)c * VOX;
        float acc = w000 * g[o000] + w001 * g[o001] + w010 * g[o010] + w011 * g[o011]
                  + w100 * g[o100] + w101 * g[o101] + w110 * g[o110] + w111 * g[o111];
        out[(size_t)c * N + n] = acc;
    }
}

extern "C" void kernel_launch(void* const* d_in, const int* in_sizes, int n_in,
                              void* d_out, int out_size, void* d_ws, size_t ws_size,
                              hipStream_t stream) {
    const float* input  = (const float*)d_in[0];
    const float* coords = (const float*)d_in[1];
    float* out = (float*)d_out;
    int N = in_sizes[1] / 3;  // 1,000,000

    size_t need = (size_t)VOX * NCH * sizeof(unsigned short);  // 67 MB bf16 channel-last
    if (ws_size >= need) {
        transpose_bf16_k<<<VOX / 4 / 256, 256, 0, stream>>>(input, (unsigned short*)d_ws);
        interp_bf16_k<<<(N + 255) / 256, 256, 0, stream>>>((const unsigned short*)d_ws,
                                                           coords, out, N);
    } else {
        interp_direct_k<<<(N + 255) / 256, 256, 0, stream>>>(input, coords, out, N);
    }
}